// Round 2
// baseline (519.147 us; speedup 1.0000x reference)
//
#include <hip/hip_runtime.h>
#include <hip/hip_bf16.h>

// Problem constants (from reference): B=64, S=2048, D_ENC=D_DEC=UNITS=512
#define BATCH 64
#define SEQ   2048
#define DIM   512
#define MROWS (BATCH * SEQ)   // 131072 rows of the big GEMM

typedef short bf16x8 __attribute__((ext_vector_type(8)));
typedef float f32x4  __attribute__((ext_vector_type(4)));

static __device__ __forceinline__ unsigned short f2bf(float f) {
    // round-to-nearest-even fp32 -> bf16
    union { float f; unsigned u; } v; v.f = f;
    unsigned u = v.u;
    u += 0x7FFFu + ((u >> 16) & 1u);
    return (unsigned short)(u >> 16);
}

// fast tanh: tanh(x) = (e^{2x}-1)/(e^{2x}+1), e^{2x} = 2^{x*2log2(e)}
static __device__ __forceinline__ float tanh_fast(float x) {
    float xc = fminf(20.0f, fmaxf(-20.0f, x));
#if __has_builtin(__builtin_amdgcn_exp2f)
    float t = __builtin_amdgcn_exp2f(2.885390082f * xc);
#else
    float t = exp2f(2.885390082f * xc);
#endif
#if __has_builtin(__builtin_amdgcn_rcpf)
    return (t - 1.0f) * __builtin_amdgcn_rcpf(t + 1.0f);
#else
    return (t - 1.0f) / (t + 1.0f);
#endif
}

// global -> LDS async DMA, 16B per lane. LDS dest must be wave-uniform base
// + lane*16 (m104/m108 caveat) — our chunk ids are lane-consecutive.
typedef __attribute__((address_space(1))) const unsigned int gu32;
typedef __attribute__((address_space(3))) unsigned int lu32;
static __device__ __forceinline__ void gload_lds16(const unsigned short* g,
                                                   unsigned short* l) {
    __builtin_amdgcn_global_load_lds((gu32*)g, (lu32*)l, 16, 0, 0);
}

// ---------------------------------------------------------------------------
// Kernel 0: W1 [k][u] fp32  ->  W1t [u][k] bf16   (512x512, tiny)
// ---------------------------------------------------------------------------
__global__ void prep_w1t_kernel(const float* __restrict__ W1,
                                unsigned short* __restrict__ w1t) {
    int stride = gridDim.x * blockDim.x;
    for (int i = blockIdx.x * blockDim.x + threadIdx.x; i < DIM * DIM; i += stride) {
        int k = i >> 9;
        int u = i & 511;
        w1t[u * DIM + k] = f2bf(W1[i]);
    }
}

// ---------------------------------------------------------------------------
// Kernel 1 (v2): pd[b][u] = dec[b,:] @ W2[:,u] + b1[u] + b2[u]
// grid (8 u-groups, 64 b), 256 threads = 64 u x 4 k-quarters.
// ---------------------------------------------------------------------------
__global__ void proj_dec_v2(const float* __restrict__ dec,
                            const float* __restrict__ W2,
                            const float* __restrict__ b1,
                            const float* __restrict__ b2,
                            float* __restrict__ pd) {
    __shared__ float sdec[DIM];
    __shared__ float red[4 * 64];
    const int ug = blockIdx.x;      // 0..7  -> u0 = ug*64
    const int b  = blockIdx.y;      // 0..63
    const int t  = threadIdx.x;     // 256
    sdec[t]       = dec[b * DIM + t];
    sdec[t + 256] = dec[b * DIM + t + 256];
    __syncthreads();
    const int u  = ug * 64 + (t & 63);
    const int kq = t >> 6;          // 0..3
    float acc = 0.f;
    #pragma unroll 4
    for (int k = kq * 128; k < kq * 128 + 128; ++k)
        acc += sdec[k] * W2[k * DIM + u];
    red[kq * 64 + (t & 63)] = acc;
    __syncthreads();
    if (t < 64) {
        int u_g = ug * 64 + t;
        float s = red[t] + red[64 + t] + red[128 + t] + red[192 + t]
                + b1[u_g] + b2[u_g];
        pd[b * DIM + u_g] = s;
    }
}

// ---------------------------------------------------------------------------
// Kernel 2 (v5): 64x512 block, 4 waves. NEW: double-buffered LDS (144 KB,
// 1 block/CU) with ONE barrier per K-round (T3 minimum-2-phase): next round's
// B-DMA + A ds_write are issued into buf^1 BEFORE computing buf, so the loads
// fly under the MFMA phase and the single __syncthreads drain finds them
// landed. A is additionally register-prefetched one round ahead (T14) so the
// fp32->bf16 convert never waits on HBM. Math/order identical to v4.
// ---------------------------------------------------------------------------
#define BM3 64
#define BK3 64
#define NK3 (DIM / BK3)   // 8 K-rounds

__global__ __launch_bounds__(256, 1) void gemm_score_v5(
    const float* __restrict__ enc,            // [m][k] fp32
    const unsigned short* __restrict__ w1t,   // [u][k] bf16
    const float* __restrict__ pd,             // [b][u]
    const float* __restrict__ V,              // [u]
    float* __restrict__ scores)               // [M]
{
    __shared__ unsigned short sA[2][BM3 * BK3];   // 2 x 8 KB
    __shared__ unsigned short sB[2][DIM * BK3];   // 2 x 64 KB

    const int tid  = threadIdx.x;
    const int lane = tid & 63;
    const int wave = tid >> 6;        // 0..3 -> col strip wave*128
    const int quad = lane >> 4;
    const int l15  = lane & 15;

    const int row0 = blockIdx.x * BM3;   // gridDim.x = 2048

    f32x4 acc[8][4];   // [j: col subtile 16][tr: row subtile 16]
    for (int j = 0; j < 8; ++j)
        for (int tr = 0; tr < 4; ++tr)
            acc[j][tr] = (f32x4){0.f, 0.f, 0.f, 0.f};

    // A-prefetch registers: 2 chunks x 2 float4 (chunk c = i*256+tid)
    float4 pa[2][2];

    // --- helpers (manually inlined as loops; wave-uniform control flow) ---
    // chunk geometry: c = i*256+tid; r = c>>3 (row); cc = c&7 (k-octet)

    // prologue: load A(k=0), DMA B(k=0), write A(k=0), prefetch A(k=64)
    {
        for (int i = 0; i < 2; ++i) {
            int c = i * 256 + tid, r = c >> 3, cc = c & 7;
            const float4* p = (const float4*)(enc + (size_t)(row0 + r) * DIM + cc * 8);
            pa[i][0] = p[0]; pa[i][1] = p[1];
        }
        for (int i = 0; i < 16; ++i) {
            int c = i * 256 + tid, r = c >> 3, cc = c & 7;
            int gc = cc ^ (r & 7);
            gload_lds16(w1t + (size_t)r * DIM + gc * 8, &sB[0][c * 8]);
        }
        for (int i = 0; i < 2; ++i) {
            int c = i * 256 + tid, r = c >> 3, cc = c & 7;
            union { ushort4 s[2]; uint4 q; } o;
            o.s[0].x = f2bf(pa[i][0].x); o.s[0].y = f2bf(pa[i][0].y);
            o.s[0].z = f2bf(pa[i][0].z); o.s[0].w = f2bf(pa[i][0].w);
            o.s[1].x = f2bf(pa[i][1].x); o.s[1].y = f2bf(pa[i][1].y);
            o.s[1].z = f2bf(pa[i][1].z); o.s[1].w = f2bf(pa[i][1].w);
            *(uint4*)(&sA[0][r * BK3 + ((cc ^ (r & 7)) * 8)]) = o.q;
        }
        for (int i = 0; i < 2; ++i) {
            int c = i * 256 + tid, r = c >> 3, cc = c & 7;
            const float4* p = (const float4*)(enc + (size_t)(row0 + r) * DIM + BK3 + cc * 8);
            pa[i][0] = p[0]; pa[i][1] = p[1];
        }
    }
    __syncthreads();

    for (int t = 0; t < NK3; ++t) {
        const int cur = t & 1, nxt = cur ^ 1;

        // phase 1: stage round t+1 into the other buffer (flies under MFMA)
        if (t < NK3 - 1) {
            const int k1 = (t + 1) * BK3;
            for (int i = 0; i < 16; ++i) {
                int c = i * 256 + tid, r = c >> 3, cc = c & 7;
                int gc = cc ^ (r & 7);
                gload_lds16(w1t + (size_t)r * DIM + k1 + gc * 8, &sB[nxt][c * 8]);
            }
            for (int i = 0; i < 2; ++i) {
                int c = i * 256 + tid, r = c >> 3, cc = c & 7;
                union { ushort4 s[2]; uint4 q; } o;
                o.s[0].x = f2bf(pa[i][0].x); o.s[0].y = f2bf(pa[i][0].y);
                o.s[0].z = f2bf(pa[i][0].z); o.s[0].w = f2bf(pa[i][0].w);
                o.s[1].x = f2bf(pa[i][1].x); o.s[1].y = f2bf(pa[i][1].y);
                o.s[1].z = f2bf(pa[i][1].z); o.s[1].w = f2bf(pa[i][1].w);
                *(uint4*)(&sA[nxt][r * BK3 + ((cc ^ (r & 7)) * 8)]) = o.q;
            }
            if (t < NK3 - 2) {
                const int k2 = (t + 2) * BK3;
                for (int i = 0; i < 2; ++i) {
                    int c = i * 256 + tid, r = c >> 3, cc = c & 7;
                    const float4* p =
                        (const float4*)(enc + (size_t)(row0 + r) * DIM + k2 + cc * 8);
                    pa[i][0] = p[0]; pa[i][1] = p[1];
                }
            }
        }

        // phase 2: MFMA on buffer cur
        for (int kk = 0; kk < BK3; kk += 32) {
            int jc = (kk >> 3) + quad;   // global k-chunk 0..7
            bf16x8 af[4];
            for (int tr = 0; tr < 4; ++tr) {
                int am = tr * 16 + l15;
                af[tr] = *(const bf16x8*)(&sA[cur][am * BK3 + ((jc ^ (am & 7)) * 8)]);
            }
            for (int j = 0; j < 8; ++j) {
                int u = wave * 128 + j * 16 + l15;
                bf16x8 bfr = *(const bf16x8*)(&sB[cur][u * BK3 + ((jc ^ (u & 7)) * 8)]);
                for (int tr = 0; tr < 4; ++tr)
                    acc[j][tr] = __builtin_amdgcn_mfma_f32_16x16x32_bf16(
                        af[tr], bfr, acc[j][tr], 0, 0, 0);
            }
        }
        __syncthreads();   // reads of cur done; writes to nxt landed
    }

    // epilogue: tanh + V-dot over this wave's 128 u's
    const int b = row0 >> 11;   // 64-row blocks never cross a batch
    float sacc[4][4];
    for (int tr = 0; tr < 4; ++tr)
        for (int r = 0; r < 4; ++r) sacc[tr][r] = 0.f;

    for (int j = 0; j < 8; ++j) {
        int u_g   = wave * 128 + j * 16 + l15;
        float pdv = pd[b * DIM + u_g];
        float vv  = V[u_g];
        for (int tr = 0; tr < 4; ++tr)
            for (int r = 0; r < 4; ++r)
                sacc[tr][r] += tanh_fast(acc[j][tr][r] + pdv) * vv;
    }
    // reduce across the 16 col-lanes (lane bits 0..3)
    for (int tr = 0; tr < 4; ++tr)
        for (int r = 0; r < 4; ++r) {
            float v = sacc[tr][r];
            v += __shfl_xor(v, 1);
            v += __shfl_xor(v, 2);
            v += __shfl_xor(v, 4);
            v += __shfl_xor(v, 8);
            sacc[tr][r] = v;
        }
    // cross-wave reduce via LDS (reuse sA[0]; last read of sA[0] was round 6,
    // fenced by the loop's final __syncthreads)
    float* red = (float*)sA;   // 4 waves x 64 rows = 1 KB
    if (l15 == 0) {
        for (int tr = 0; tr < 4; ++tr)
            for (int r = 0; r < 4; ++r)
                red[wave * BM3 + tr * 16 + quad * 4 + r] = sacc[tr][r];
    }
    __syncthreads();
    if (tid < BM3) {
        float s = red[tid] + red[BM3 + tid] + red[2 * BM3 + tid] + red[3 * BM3 + tid];
        scores[row0 + tid] = s;
    }
}

// ---------------------------------------------------------------------------
// Kernel 3 (v2): fused softmax + context, 512 threads (16 waves/CU for
// latency hiding on the strided enc reads). Reduce scratch padded to
// stride 65 to kill the 16-way bank conflict on partial-sum writes.
// bv omitted: softmax is shift-invariant in both outputs.
// ---------------------------------------------------------------------------
__global__ __launch_bounds__(512) void softmax_context_v2(
    const float* __restrict__ scores,
    const float* __restrict__ enc,
    float* __restrict__ attn,
    float* __restrict__ ctx) {
    __shared__ float sa[SEQ];          // softmax weights, 8 KB
    __shared__ float red[64 * 65];     // reduce scratch, 16.25 KB (padded)
    const int dchunk = blockIdx.x;     // 0..7 -> dims dchunk*64..+63
    const int b      = blockIdx.y;     // 0..63
    const int t      = threadIdx.x;    // 512

    // ---- softmax over scores[b][0..2047] (identical math across the 8
    // blocks of a batch -> deterministic ctx/attn consistency) ----
    const float* sc = scores + (size_t)b * SEQ;
    float v[4];
    float mx = -1e30f;
    for (int i = 0; i < 4; ++i) {
        v[i] = sc[t + i * 512];
        mx = fmaxf(mx, v[i]);
    }
    red[t] = mx;
    __syncthreads();
    for (int off = 256; off > 0; off >>= 1) {
        if (t < off) red[t] = fmaxf(red[t], red[t + off]);
        __syncthreads();
    }
    mx = red[0];
    __syncthreads();
    float sum = 0.f;
    for (int i = 0; i < 4; ++i) {
        float e = expf(v[i] - mx);
        sa[t + i * 512] = e;
        sum += e;
    }
    red[t] = sum;
    __syncthreads();
    for (int off = 256; off > 0; off >>= 1) {
        if (t < off) red[t] += red[t + off];
        __syncthreads();
    }
    const float inv = 1.0f / red[0];
    __syncthreads();                 // everyone has read red[0]
    for (int i = 0; i < 4; ++i) sa[t + i * 512] *= inv;
    if (dchunk == 0) {
        for (int i = 0; i < 4; ++i)
            attn[(size_t)b * SEQ + t + i * 512] = sa[t + i * 512];
    }
    __syncthreads();                 // sa fully written

    // ---- weighted sum over seq for this block's 64 dims ----
    const int tl = t & 7;            // dim octet: 8 fp32 = 2x float4
    const int rg = t >> 3;           // row group 0..63
    const float* base = enc + (size_t)b * SEQ * DIM + dchunk * 64 + tl * 8;
    float a[8];
    for (int q = 0; q < 8; ++q) a[q] = 0.f;
    for (int i = 0; i < 32; ++i) {
        int r = rg + i * 64;
        float w = sa[r];
        const float4* p = (const float4*)(base + (size_t)r * DIM);
        float4 x = p[0], y = p[1];
        a[0] += w * x.x; a[1] += w * x.y; a[2] += w * x.z; a[3] += w * x.w;
        a[4] += w * y.x; a[5] += w * y.y; a[6] += w * y.z; a[7] += w * y.w;
    }
    for (int q = 0; q < 8; ++q) red[rg * 65 + tl * 8 + q] = a[q];
    __syncthreads();
    if (t < 64) {
        float s = 0.f;
        for (int g = 0; g < 64; ++g) s += red[g * 65 + t];
        ctx[(size_t)b * DIM + dchunk * 64 + t] = s;
    }
}

// ---------------------------------------------------------------------------
// Launch: 4 dispatches. Workspace need: 1.2 MB.
// ---------------------------------------------------------------------------
extern "C" void kernel_launch(void* const* d_in, const int* in_sizes, int n_in,
                              void* d_out, int out_size, void* d_ws, size_t ws_size,
                              hipStream_t stream) {
    const float* enc = (const float*)d_in[0];   // [64,2048,512]
    const float* dec = (const float*)d_in[1];   // [64,512]
    const float* W1  = (const float*)d_in[2];   // [512,512]
    const float* b1  = (const float*)d_in[3];   // [512]
    const float* W2  = (const float*)d_in[4];   // [512,512]
    const float* b2  = (const float*)d_in[5];   // [512]
    const float* V   = (const float*)d_in[6];   // [512,1]
    // d_in[7] = bv: dead (softmax shift-invariance)

    float* out  = (float*)d_out;
    float* ctx  = out;                 // [64,512]
    float* attn = out + BATCH * DIM;   // [64,2048]

    char* ws = (char*)d_ws;
    float* pd            = (float*)ws;                           // 128 KB
    unsigned short* w1t  = (unsigned short*)(ws + 131072);       // 512 KB
    float* scores        = (float*)(ws + 131072 + 524288);       // 512 KB

    prep_w1t_kernel<<<256, 256, 0, stream>>>(W1, w1t);
    proj_dec_v2<<<dim3(8, BATCH), 256, 0, stream>>>(dec, W2, b1, b2, pd);
    gemm_score_v5<<<MROWS / BM3, 256, 0, stream>>>(enc, w1t, pd, V, scores);
    softmax_context_v2<<<dim3(8, BATCH), 512, 0, stream>>>(scores, enc, attn, ctx);
}

// Round 3
// 448.086 us; speedup vs baseline: 1.1586x; 1.1586x over previous
//
#include <hip/hip_runtime.h>
#include <hip/hip_bf16.h>

// Problem constants (from reference): B=64, S=2048, D_ENC=D_DEC=UNITS=512
#define BATCH 64
#define SEQ   2048
#define DIM   512
#define MROWS (BATCH * SEQ)   // 131072 rows of the big GEMM

typedef short bf16x8 __attribute__((ext_vector_type(8)));
typedef float f32x4  __attribute__((ext_vector_type(4)));

static __device__ __forceinline__ unsigned short f2bf(float f) {
    // round-to-nearest-even fp32 -> bf16
    union { float f; unsigned u; } v; v.f = f;
    unsigned u = v.u;
    u += 0x7FFFu + ((u >> 16) & 1u);
    return (unsigned short)(u >> 16);
}

// fast tanh: tanh(x) = (e^{2x}-1)/(e^{2x}+1), e^{2x} = 2^{x*2log2(e)}
static __device__ __forceinline__ float tanh_fast(float x) {
    float xc = fminf(20.0f, fmaxf(-20.0f, x));
#if __has_builtin(__builtin_amdgcn_exp2f)
    float t = __builtin_amdgcn_exp2f(2.885390082f * xc);
#else
    float t = exp2f(2.885390082f * xc);
#endif
#if __has_builtin(__builtin_amdgcn_rcpf)
    return (t - 1.0f) * __builtin_amdgcn_rcpf(t + 1.0f);
#else
    return (t - 1.0f) / (t + 1.0f);
#endif
}

// global -> LDS async DMA, 16B per lane. LDS dest must be wave-uniform base
// + lane*16 (m104/m108 caveat) — our chunk ids are lane-consecutive.
typedef __attribute__((address_space(1))) const unsigned int gu32;
typedef __attribute__((address_space(3))) unsigned int lu32;
static __device__ __forceinline__ void gload_lds16(const unsigned short* g,
                                                   unsigned short* l) {
    __builtin_amdgcn_global_load_lds((gu32*)g, (lu32*)l, 16, 0, 0);
}

// ---------------------------------------------------------------------------
// Kernel 0: W1 [k][u] fp32  ->  W1t [u][k] bf16   (512x512, tiny)
// ---------------------------------------------------------------------------
__global__ void prep_w1t_kernel(const float* __restrict__ W1,
                                unsigned short* __restrict__ w1t) {
    int stride = gridDim.x * blockDim.x;
    for (int i = blockIdx.x * blockDim.x + threadIdx.x; i < DIM * DIM; i += stride) {
        int k = i >> 9;
        int u = i & 511;
        w1t[u * DIM + k] = f2bf(W1[i]);
    }
}

// ---------------------------------------------------------------------------
// Kernel 1 (v2): pd[b][u] = dec[b,:] @ W2[:,u] + b1[u] + b2[u]
// grid (8 u-groups, 64 b), 256 threads = 64 u x 4 k-quarters.
// ---------------------------------------------------------------------------
__global__ void proj_dec_v2(const float* __restrict__ dec,
                            const float* __restrict__ W2,
                            const float* __restrict__ b1,
                            const float* __restrict__ b2,
                            float* __restrict__ pd) {
    __shared__ float sdec[DIM];
    __shared__ float red[4 * 64];
    const int ug = blockIdx.x;      // 0..7  -> u0 = ug*64
    const int b  = blockIdx.y;      // 0..63
    const int t  = threadIdx.x;     // 256
    sdec[t]       = dec[b * DIM + t];
    sdec[t + 256] = dec[b * DIM + t + 256];
    __syncthreads();
    const int u  = ug * 64 + (t & 63);
    const int kq = t >> 6;          // 0..3
    float acc = 0.f;
    #pragma unroll 4
    for (int k = kq * 128; k < kq * 128 + 128; ++k)
        acc += sdec[k] * W2[k * DIM + u];
    red[kq * 64 + (t & 63)] = acc;
    __syncthreads();
    if (t < 64) {
        int u_g = ug * 64 + t;
        float s = red[t] + red[64 + t] + red[128 + t] + red[192 + t]
                + b1[u_g] + b2[u_g];
        pd[b * DIM + u_g] = s;
    }
}

// ---------------------------------------------------------------------------
// Kernel 2 (v6): REVERT to the proven v4 structure (single-buffer LDS 72 KB,
// 2 barriers/round, 2 blocks/CU — R2 showed explicit dbuf at 1 block/CU
// loses to implicit cross-block overlap). NEW: fused unnormalized-softmax
// context partials in the epilogue. After scores are reduced, each block
// computes e_r = expf(score_r) (no max-shift: |score| <= sum|V| ~ 20, no
// overflow), re-reads its own 64x512 enc tile (L2/L3-hot — just streamed),
// and atomically accumulates ctx_num[b][d] += sum_r e_r*enc[r][d] and
// zacc[b] += sum_r e_r. This deletes the 268 MB second enc pass entirely.
// ---------------------------------------------------------------------------
#define BM3 64
#define BK3 64

__global__ __launch_bounds__(256, 2) void gemm_score_v6(
    const float* __restrict__ enc,            // [m][k] fp32
    const unsigned short* __restrict__ w1t,   // [u][k] bf16
    const float* __restrict__ pd,             // [b][u]
    const float* __restrict__ V,              // [u]
    float* __restrict__ scores,               // [M]
    float* __restrict__ cnum,                 // [B][DIM] atomic accumulators
    float* __restrict__ zacc)                 // [B]
{
    __shared__ unsigned short sA[BM3 * BK3];   // 8 KB
    __shared__ unsigned short sB[DIM * BK3];   // 64 KB

    const int tid  = threadIdx.x;
    const int lane = tid & 63;
    const int wave = tid >> 6;        // 0..3 -> col strip wave*128
    const int quad = lane >> 4;
    const int l15  = lane & 15;

    const int row0 = blockIdx.x * BM3;   // gridDim.x = 2048

    f32x4 acc[8][4];   // [j: col subtile 16][tr: row subtile 16]
    for (int j = 0; j < 8; ++j)
        for (int tr = 0; tr < 4; ++tr)
            acc[j][tr] = (f32x4){0.f, 0.f, 0.f, 0.f};

    for (int k0 = 0; k0 < DIM; k0 += BK3) {
        // stage B first (async DMA): 512 u's x 64 k = 4096 chunks, 16/thread
        for (int i = 0; i < 16; ++i) {
            int c  = i * 256 + tid;
            int r  = c >> 3;          // u = 0..511
            int cc = c & 7;
            int gc = cc ^ (r & 7);
            gload_lds16(w1t + (size_t)r * DIM + k0 + gc * 8, &sB[c * 8]);
        }
        // stage A: 64 rows x 64 k fp32 -> bf16 in-register, 512 chunks,
        // 2/thread; XOR swizzle applied on the LDS write address.
        for (int i = 0; i < 2; ++i) {
            int c  = i * 256 + tid;
            int r  = c >> 3;
            int cc = c & 7;
            const float4* p =
                (const float4*)(enc + (size_t)(row0 + r) * DIM + k0 + cc * 8);
            float4 va = p[0], vb = p[1];
            union { ushort4 s[2]; uint4 q; } o;
            o.s[0].x = f2bf(va.x); o.s[0].y = f2bf(va.y);
            o.s[0].z = f2bf(va.z); o.s[0].w = f2bf(va.w);
            o.s[1].x = f2bf(vb.x); o.s[1].y = f2bf(vb.y);
            o.s[1].z = f2bf(vb.z); o.s[1].w = f2bf(vb.w);
            *(uint4*)(&sA[r * BK3 + ((cc ^ (r & 7)) * 8)]) = o.q;
        }
        __syncthreads();

        for (int kk = 0; kk < BK3; kk += 32) {
            int jc = (kk >> 3) + quad;   // global k-chunk 0..7
            bf16x8 af[4];
            for (int tr = 0; tr < 4; ++tr) {
                int am = tr * 16 + l15;
                af[tr] = *(const bf16x8*)(&sA[am * BK3 + ((jc ^ (am & 7)) * 8)]);
            }
            for (int j = 0; j < 8; ++j) {
                int u = wave * 128 + j * 16 + l15;
                bf16x8 bfr = *(const bf16x8*)(&sB[u * BK3 + ((jc ^ (u & 7)) * 8)]);
                for (int tr = 0; tr < 4; ++tr)
                    acc[j][tr] = __builtin_amdgcn_mfma_f32_16x16x32_bf16(
                        af[tr], bfr, acc[j][tr], 0, 0, 0);
            }
        }
        __syncthreads();
    }

    // ---- epilogue part 1: tanh + V-dot over this wave's 128 u's ----
    const int b = row0 >> 11;   // 64-row blocks never cross a batch
    float sacc[4][4];
    for (int tr = 0; tr < 4; ++tr)
        for (int r = 0; r < 4; ++r) sacc[tr][r] = 0.f;

    for (int j = 0; j < 8; ++j) {
        int u_g   = wave * 128 + j * 16 + l15;
        float pdv = pd[b * DIM + u_g];
        float vv  = V[u_g];
        for (int tr = 0; tr < 4; ++tr)
            for (int r = 0; r < 4; ++r)
                sacc[tr][r] += tanh_fast(acc[j][tr][r] + pdv) * vv;
    }
    // reduce across the 16 col-lanes (lane bits 0..3)
    for (int tr = 0; tr < 4; ++tr)
        for (int r = 0; r < 4; ++r) {
            float v = sacc[tr][r];
            v += __shfl_xor(v, 1);
            v += __shfl_xor(v, 2);
            v += __shfl_xor(v, 4);
            v += __shfl_xor(v, 8);
            sacc[tr][r] = v;
        }
    // cross-wave reduce via LDS (reuse sA; fenced by the loop's last barrier)
    float* red  = (float*)sA;           // 4 waves x 64 rows = 1 KB
    float* eLds = ((float*)sA) + 256;   // 64 floats of e^score
    if (l15 == 0) {
        for (int tr = 0; tr < 4; ++tr)
            for (int r = 0; r < 4; ++r)
                red[wave * BM3 + tr * 16 + quad * 4 + r] = sacc[tr][r];
    }
    __syncthreads();
    if (tid < BM3) {
        float s = red[tid] + red[BM3 + tid] + red[2 * BM3 + tid] + red[3 * BM3 + tid];
        scores[row0 + tid] = s;
        eLds[tid] = expf(s);    // unnormalized softmax numerator
    }
    __syncthreads();

    // ---- epilogue part 2: context partials (no second enc pass later) ----
    // zacc partial: wave 0 reduces the 64 e-values
    if (wave == 0) {
        float e = eLds[lane];
        e += __shfl_xor(e, 32);
        e += __shfl_xor(e, 16);
        e += __shfl_xor(e, 8);
        e += __shfl_xor(e, 4);
        e += __shfl_xor(e, 2);
        e += __shfl_xor(e, 1);
        if (lane == 0) atomicAdd(&zacc[b], e);
    }
    // cnum partial: thread owns dims 2*tid, 2*tid+1; rows re-read from L2-hot
    // enc (per-row the 256 threads read a contiguous 2 KB line).
    {
        const int d = tid * 2;
        const float* ebase = enc + (size_t)row0 * DIM + d;
        float cx = 0.f, cy = 0.f;
        #pragma unroll 4
        for (int r = 0; r < BM3; ++r) {
            float w = eLds[r];
            float2 x = *(const float2*)(ebase + (size_t)r * DIM);
            cx += w * x.x;
            cy += w * x.y;
        }
        atomicAdd(&cnum[b * DIM + d],     cx);
        atomicAdd(&cnum[b * DIM + d + 1], cy);
    }
}

// ---------------------------------------------------------------------------
// Kernel 3: finalize — normalize attn and ctx. grid (4 seq-chunks, 64 b).
// expf(scores) here is bit-identical to the epilogue's (same stored input,
// same function), so attn sums to 1 within fp error.
// ---------------------------------------------------------------------------
__global__ void finalize_kernel(const float* __restrict__ scores,
                                const float* __restrict__ cnum,
                                const float* __restrict__ zacc,
                                float* __restrict__ attn,
                                float* __restrict__ ctx) {
    const int c = blockIdx.x;   // 0..3
    const int b = blockIdx.y;   // 0..63
    const int t = threadIdx.x;  // 256
    const float invZ = 1.0f / zacc[b];
    for (int i = 0; i < 2; ++i) {
        int s = c * 512 + t + i * 256;
        attn[(size_t)b * SEQ + s] = expf(scores[(size_t)b * SEQ + s]) * invZ;
    }
    if (c == 0) {
        ctx[b * DIM + t]       = cnum[b * DIM + t]       * invZ;
        ctx[b * DIM + t + 256] = cnum[b * DIM + t + 256] * invZ;
    }
}

// ---------------------------------------------------------------------------
// Launch: memset(131.3 KB) + 4 kernels. Workspace need: ~1.3 MB.
// ---------------------------------------------------------------------------
extern "C" void kernel_launch(void* const* d_in, const int* in_sizes, int n_in,
                              void* d_out, int out_size, void* d_ws, size_t ws_size,
                              hipStream_t stream) {
    const float* enc = (const float*)d_in[0];   // [64,2048,512]
    const float* dec = (const float*)d_in[1];   // [64,512]
    const float* W1  = (const float*)d_in[2];   // [512,512]
    const float* b1  = (const float*)d_in[3];   // [512]
    const float* W2  = (const float*)d_in[4];   // [512,512]
    const float* b2  = (const float*)d_in[5];   // [512]
    const float* V   = (const float*)d_in[6];   // [512,1]
    // d_in[7] = bv: dead (softmax shift-invariance)

    float* out  = (float*)d_out;
    float* ctx  = out;                 // [64,512]
    float* attn = out + BATCH * DIM;   // [64,2048]

    char* ws = (char*)d_ws;
    float* pd            = (float*)ws;                                  // 128 KB
    unsigned short* w1t  = (unsigned short*)(ws + 131072);              // 512 KB
    float* scores        = (float*)(ws + 131072 + 524288);              // 512 KB
    float* cnum          = (float*)(ws + 131072 + 524288 + 524288);     // 128 KB
    float* zacc          = (float*)(ws + 131072 + 524288 + 524288 + 131072); // 256 B

    // zero the atomic accumulators (cnum + zacc are contiguous)
    hipMemsetAsync(cnum, 0, (size_t)BATCH * DIM * 4 + BATCH * 4, stream);

    prep_w1t_kernel<<<256, 256, 0, stream>>>(W1, w1t);
    proj_dec_v2<<<dim3(8, BATCH), 256, 0, stream>>>(dec, W2, b1, b2, pd);
    gemm_score_v6<<<MROWS / BM3, 256, 0, stream>>>(enc, w1t, pd, V, scores,
                                                   cnum, zacc);
    finalize_kernel<<<dim3(4, BATCH), 256, 0, stream>>>(scores, cnum, zacc,
                                                        attn, ctx);
}